// Round 10
// baseline (25.234 us; speedup 1.0000x reference)
//
#include <hip/hip_runtime.h>
#include <float.h>
#include <math.h>

// Problem constants (from reference)
constexpr int B  = 16;
constexpr int VS = 10475;
constexpr int VO = 8192;
constexpr int K  = 64;
constexpr int PS = 1024;
constexpr int PO = 2048;

// Geometry (R6-proven): 256 blocks (1/CU) x 256 threads (4 waves).
// Block = (k, 256-query chunk). 8 half-wave jgroups; each lane owns 8
// queries (4 packed f32 pairs).
// R10: (a) object gather double-buffered in 2 halves of 1024 so half-2's
// global loads hide under half-1's compute; (b) j-paired hot loop with
// fused v_min3_f32 (6 pk_fma + 2 min3 per 2obj x 2q).
constexpr int BLK   = 256;
constexpr int QPB   = 256;              // queries per block
constexpr int GRID  = K * (PS / QPB);   // 256
constexpr int NG    = 8;                // jgroups (half-waves)
constexpr int HALF  = PO / 2;           // 1024 objects per half
constexpr int JPH   = HALF / NG;        // 128 objects per jgroup per half
constexpr int QL    = 8;                // queries per lane (4 pairs)
constexpr int OPT   = HALF / BLK;       // 4 objects per thread per half

typedef float v2f __attribute__((ext_vector_type(2)));
typedef float v4f __attribute__((ext_vector_type(4)));

// ---------------- kernel 1: full min + block partial sum ----------------

__global__ __launch_bounds__(BLK)
void cl_onepass(const float* __restrict__ smplx_v,
                const float* __restrict__ object_v,
                const int*   __restrict__ spi,
                const int*   __restrict__ opi,
                const int*   __restrict__ bidx,
                float*       __restrict__ partial)   // [GRID]
{
    __shared__ v4f    soA[HALF];     // 16 KiB  (x,y,z, 0.5*|o|^2)
    __shared__ v4f    soB[HALF];     // 16 KiB
    __shared__ float4 qld[QPB];      //  4 KiB  (x,y,z, |s|^2)
    __shared__ float  red[NG][QPB];  //  8 KiB
    __shared__ float  rsum[BLK];     //  1 KiB

    const int bk  = blockIdx.x;
    const int tid = threadIdx.x;
    const int k   = bk >> 2;
    const int ic  = bk & 3;
    const int b   = bidx[k];

    const float* __restrict__ ov   = object_v + (size_t)b * VO * 3;
    const int*   __restrict__ opik = opi + k * PO;

    // ---- issue half-0 object loads ----
    float x0[OPT], y0[OPT], z0[OPT];
    #pragma unroll
    for (int r = 0; r < OPT; ++r) {
        const int oj = opik[r * BLK + tid];
        x0[r] = ov[oj * 3 + 0];
        y0[r] = ov[oj * 3 + 1];
        z0[r] = ov[oj * 3 + 2];
    }

    // ---- gather this block's 256 queries (overlaps load latency) ----
    {
        const int i  = ic * QPB + tid;
        const int si = spi[k * PS + i];
        const float* __restrict__ sv = smplx_v + ((size_t)b * VS + si) * 3;
        const float x = sv[0], y = sv[1], z = sv[2];
        qld[tid] = make_float4(x, y, z, x * x + y * y + z * z);
    }

    // ---- write half 0 ----
    #pragma unroll
    for (int r = 0; r < OPT; ++r)
        soA[r * BLK + tid] =
            (v4f){x0[r], y0[r], z0[r],
                  0.5f * (x0[r] * x0[r] + y0[r] * y0[r] + z0[r] * z0[r])};
    __syncthreads();

    // ---- issue half-1 object loads (hide under half-0 compute) ----
    float x1[OPT], y1[OPT], z1[OPT];
    #pragma unroll
    for (int r = 0; r < OPT; ++r) {
        const int oj = opik[HALF + r * BLK + tid];
        x1[r] = ov[oj * 3 + 0];
        y1[r] = ov[oj * 3 + 1];
        z1[r] = ov[oj * 3 + 2];
    }

    // ---- setup: lane owns 8 queries as 4 packed pairs ----
    const int g  = tid >> 5;         // jgroup 0..7 (half-wave)
    const int gl = tid & 31;
    const int qb = gl * QL;

    v2f nsx[4], nsy[4], nsz[4], mint[4];
    #pragma unroll
    for (int p = 0; p < 4; ++p) {
        const float4 qa = qld[qb + 2 * p];
        const float4 qc = qld[qb + 2 * p + 1];
        nsx[p] = (v2f){-qa.x, -qc.x};
        nsy[p] = (v2f){-qa.y, -qc.y};
        nsz[p] = (v2f){-qa.z, -qc.z};
        mint[p] = (v2f){FLT_MAX, FLT_MAX};
    }

    // ---- hot loop (R6-proven pk_fma op_sel asm; j-paired + min3) ----
    // t = 0.5*|o|^2 - s.o for 2 queries per v_pk_fma_f32; op_sel splats
    // the object components from the (x,y),(z,w) register pairs.
    auto run_half = [&](const v4f* __restrict__ soH) {
        #pragma unroll 4
        for (int m = 0; m < JPH / 2; ++m) {
            const v4f o0 = soH[2 * m];
            const v4f o1 = soH[2 * m + 1];
            const v2f o0xy = __builtin_shufflevector(o0, o0, 0, 1);
            const v2f o0zw = __builtin_shufflevector(o0, o0, 2, 3);
            const v2f o1xy = __builtin_shufflevector(o1, o1, 0, 1);
            const v2f o1zw = __builtin_shufflevector(o1, o1, 2, 3);
            #pragma unroll
            for (int p = 0; p < 4; ++p) {
                v2f t0, t1;
                asm("v_pk_fma_f32 %0, %1, %2, %3 op_sel:[0,0,1] op_sel_hi:[0,1,1]"
                    : "=v"(t0) : "v"(o0xy), "v"(nsx[p]), "v"(o0zw));
                asm("v_pk_fma_f32 %0, %1, %2, %0 op_sel:[1,0,0] op_sel_hi:[1,1,1]"
                    : "+v"(t0) : "v"(o0xy), "v"(nsy[p]));
                asm("v_pk_fma_f32 %0, %1, %2, %0 op_sel:[0,0,0] op_sel_hi:[0,1,1]"
                    : "+v"(t0) : "v"(o0zw), "v"(nsz[p]));
                asm("v_pk_fma_f32 %0, %1, %2, %3 op_sel:[0,0,1] op_sel_hi:[0,1,1]"
                    : "=v"(t1) : "v"(o1xy), "v"(nsx[p]), "v"(o1zw));
                asm("v_pk_fma_f32 %0, %1, %2, %0 op_sel:[1,0,0] op_sel_hi:[1,1,1]"
                    : "+v"(t1) : "v"(o1xy), "v"(nsy[p]));
                asm("v_pk_fma_f32 %0, %1, %2, %0 op_sel:[0,0,0] op_sel_hi:[0,1,1]"
                    : "+v"(t1) : "v"(o1zw), "v"(nsz[p]));
                mint[p].x = fminf(mint[p].x, fminf(t0.x, t1.x));   // v_min3_f32
                mint[p].y = fminf(mint[p].y, fminf(t0.y, t1.y));
            }
        }
    };

    run_half(&soA[g * JPH]);

    // ---- write half 1 (loads have landed during half-0 compute) ----
    #pragma unroll
    for (int r = 0; r < OPT; ++r)
        soB[r * BLK + tid] =
            (v4f){x1[r], y1[r], z1[r],
                  0.5f * (x1[r] * x1[r] + y1[r] * y1[r] + z1[r] * z1[r])};
    __syncthreads();

    run_half(&soB[g * JPH]);

    // ---- cross-jgroup min via LDS ----
    #pragma unroll
    for (int p = 0; p < 4; ++p) {
        red[g][qb + 2 * p]     = mint[p].x;
        red[g][qb + 2 * p + 1] = mint[p].y;
    }
    __syncthreads();

    // thread t finalizes query t of this block
    float mq = red[0][tid];
    #pragma unroll
    for (int g2 = 1; g2 < NG; ++g2) mq = fminf(mq, red[g2][tid]);
    const float s2q = qld[tid].w;
    const float d   = sqrtf(fmaxf(fmaf(2.0f, mq, s2q), 0.0f));

    // ---- deterministic block tree-sum ----
    rsum[tid] = d;
    __syncthreads();
    for (int s = BLK / 2; s > 0; s >>= 1) {
        if (tid < s) rsum[tid] += rsum[tid + s];
        __syncthreads();
    }
    if (tid == 0) partial[bk] = rsum[0];
}

// ---------------- kernel 2: final 256 -> 1 reduce (one wave) ----------------

__global__ __launch_bounds__(64)
void cl_final(const float* __restrict__ partial, float* __restrict__ out)
{
    const int t = threadIdx.x;
    const float4 a = ((const float4*)partial)[t];   // 64 lanes x 4 = 256
    float v = (a.x + a.y) + (a.z + a.w);
    #pragma unroll
    for (int off = 32; off > 0; off >>= 1)
        v += __shfl_down(v, off, 64);
    if (t == 0) out[0] = v * (1.0f / (float)(K * PS));
}

// ---------------- launcher ----------------

extern "C" void kernel_launch(void* const* d_in, const int* in_sizes, int n_in,
                              void* d_out, int out_size, void* d_ws, size_t ws_size,
                              hipStream_t stream)
{
    const float* smplx_v       = (const float*)d_in[0];
    const float* object_v      = (const float*)d_in[1];
    const int*   smpl_part_idx = (const int*)d_in[2];
    const int*   obj_part_idx  = (const int*)d_in[3];
    const int*   batch_idx     = (const int*)d_in[4];
    float*       out           = (float*)d_out;

    float* partial = (float*)d_ws;   // GRID floats

    cl_onepass<<<GRID, BLK, 0, stream>>>(
        smplx_v, object_v, smpl_part_idx, obj_part_idx, batch_idx, partial);
    cl_final<<<1, 64, 0, stream>>>(partial, out);
}

// Round 11
// 22.115 us; speedup vs baseline: 1.1410x; 1.1410x over previous
//
#include <hip/hip_runtime.h>
#include <float.h>
#include <math.h>

// Problem constants (from reference)
constexpr int B  = 16;
constexpr int VS = 10475;
constexpr int VO = 8192;
constexpr int K  = 64;
constexpr int PS = 1024;
constexpr int PO = 2048;

// Geometry: R6 skeleton (256 blocks x 256 threads, block = (k, 256-query
// chunk), all 2048 objects staged in LDS), with ONE change:
// FULL-WAVE jgroups (NG=4, one per wave). Every ds_read_b128 in the hot
// loop is a single-address 64-lane broadcast (cheapest LDS access mode);
// each wave covers its own 512 objects x all 256 queries (QL=4 per lane).
constexpr int BLK  = 256;
constexpr int QPB  = 256;              // queries per block
constexpr int GRID = K * (PS / QPB);   // 256
constexpr int NG   = 4;                // jgroups = waves per block
constexpr int JPG  = PO / NG;          // 512 objects per jgroup
constexpr int QL   = 4;                // queries per lane (2 packed pairs)

typedef float v2f __attribute__((ext_vector_type(2)));
typedef float v4f __attribute__((ext_vector_type(4)));

// ---------------- kernel 1: full min + block partial sum ----------------

__global__ __launch_bounds__(BLK)
void cl_onepass(const float* __restrict__ smplx_v,
                const float* __restrict__ object_v,
                const int*   __restrict__ spi,
                const int*   __restrict__ opi,
                const int*   __restrict__ bidx,
                float*       __restrict__ partial)   // [GRID]
{
    __shared__ v4f    so[PO];        // (x,y,z, 0.5*|o|^2) -> 32 KiB
    __shared__ float4 qld[QPB];      // (x,y,z, |s|^2)     ->  4 KiB
    __shared__ float  red[NG][QPB];  //                    ->  4 KiB
    __shared__ float  rsum[BLK];     //                    ->  1 KiB

    const int bk  = blockIdx.x;
    const int tid = threadIdx.x;
    const int k   = bk >> 2;
    const int ic  = bk & 3;
    const int b   = bidx[k];

    // ---- gather: all 2048 objects of this k into LDS (R6-identical) ----
    const float* __restrict__ ov = object_v + (size_t)b * VO * 3;
    #pragma unroll
    for (int r = 0; r < PO / BLK; ++r) {
        const int j  = r * BLK + tid;
        const int oj = opi[k * PO + j];
        const float x = ov[oj * 3 + 0];
        const float y = ov[oj * 3 + 1];
        const float z = ov[oj * 3 + 2];
        so[j] = (v4f){x, y, z, 0.5f * (x * x + y * y + z * z)};
    }
    // ---- gather: this block's 256 queries (R6-identical) ----
    {
        const int i  = ic * QPB + tid;
        const int si = spi[k * PS + i];
        const float* __restrict__ sv = smplx_v + ((size_t)b * VS + si) * 3;
        const float x = sv[0], y = sv[1], z = sv[2];
        qld[tid] = make_float4(x, y, z, x * x + y * y + z * z);
    }
    __syncthreads();

    // ---- setup: lane owns 4 queries as 2 packed pairs ----
    const int g    = tid >> 6;       // jgroup == wave id (0..3)
    const int lane = tid & 63;
    const int qb   = lane * QL;

    v2f nsx[2], nsy[2], nsz[2], mint[2];
    #pragma unroll
    for (int p = 0; p < 2; ++p) {
        const float4 qa = qld[qb + 2 * p];
        const float4 qc = qld[qb + 2 * p + 1];
        nsx[p] = (v2f){-qa.x, -qc.x};
        nsy[p] = (v2f){-qa.y, -qc.y};
        nsz[p] = (v2f){-qa.z, -qc.z};
        mint[p] = (v2f){FLT_MAX, FLT_MAX};
    }

    // ---- hot loop (R6-proven asm, unpaired): this wave's 512 objects ----
    // Every iteration: ONE broadcast ds_read_b128 (uniform address across
    // the wave) + 6 v_pk_fma_f32 + 4 v_min_f32. op_sel splats the object
    // components straight out of the (x,y),(z,w) register pairs.
    const v4f* __restrict__ sog = &so[g * JPG];
    #pragma unroll 8
    for (int j = 0; j < JPG; ++j) {
        const v4f o = sog[j];
        const v2f oxy = __builtin_shufflevector(o, o, 0, 1);  // (x,y)
        const v2f ozw = __builtin_shufflevector(o, o, 2, 3);  // (z,w)
        #pragma unroll
        for (int p = 0; p < 2; ++p) {
            v2f t;
            asm("v_pk_fma_f32 %0, %1, %2, %3 op_sel:[0,0,1] op_sel_hi:[0,1,1]"
                : "=v"(t) : "v"(oxy), "v"(nsx[p]), "v"(ozw));
            asm("v_pk_fma_f32 %0, %1, %2, %0 op_sel:[1,0,0] op_sel_hi:[1,1,1]"
                : "+v"(t) : "v"(oxy), "v"(nsy[p]));
            asm("v_pk_fma_f32 %0, %1, %2, %0 op_sel:[0,0,0] op_sel_hi:[0,1,1]"
                : "+v"(t) : "v"(ozw), "v"(nsz[p]));
            mint[p].x = fminf(mint[p].x, t.x);
            mint[p].y = fminf(mint[p].y, t.y);
        }
    }

    // ---- cross-jgroup min via LDS ----
    #pragma unroll
    for (int p = 0; p < 2; ++p) {
        red[g][qb + 2 * p]     = mint[p].x;
        red[g][qb + 2 * p + 1] = mint[p].y;
    }
    __syncthreads();

    // thread t finalizes query t of this block
    float mq = red[0][tid];
    #pragma unroll
    for (int g2 = 1; g2 < NG; ++g2) mq = fminf(mq, red[g2][tid]);
    const float s2q = qld[tid].w;
    const float d   = sqrtf(fmaxf(fmaf(2.0f, mq, s2q), 0.0f));

    // ---- deterministic block tree-sum ----
    rsum[tid] = d;
    __syncthreads();
    for (int s = BLK / 2; s > 0; s >>= 1) {
        if (tid < s) rsum[tid] += rsum[tid + s];
        __syncthreads();
    }
    if (tid == 0) partial[bk] = rsum[0];
}

// ---------------- kernel 2: final 256 -> 1 reduce (one wave) ----------------

__global__ __launch_bounds__(64)
void cl_final(const float* __restrict__ partial, float* __restrict__ out)
{
    const int t = threadIdx.x;
    const float4 a = ((const float4*)partial)[t];   // 64 lanes x 4 = 256
    float v = (a.x + a.y) + (a.z + a.w);
    #pragma unroll
    for (int off = 32; off > 0; off >>= 1)
        v += __shfl_down(v, off, 64);
    if (t == 0) out[0] = v * (1.0f / (float)(K * PS));
}

// ---------------- launcher ----------------

extern "C" void kernel_launch(void* const* d_in, const int* in_sizes, int n_in,
                              void* d_out, int out_size, void* d_ws, size_t ws_size,
                              hipStream_t stream)
{
    const float* smplx_v       = (const float*)d_in[0];
    const float* object_v      = (const float*)d_in[1];
    const int*   smpl_part_idx = (const int*)d_in[2];
    const int*   obj_part_idx  = (const int*)d_in[3];
    const int*   batch_idx     = (const int*)d_in[4];
    float*       out           = (float*)d_out;

    float* partial = (float*)d_ws;   // GRID floats

    cl_onepass<<<GRID, BLK, 0, stream>>>(
        smplx_v, object_v, smpl_part_idx, obj_part_idx, batch_idx, partial);
    cl_final<<<1, 64, 0, stream>>>(partial, out);
}